// Round 2
// baseline (188.631 us; speedup 1.0000x reference)
//
#include <hip/hip_runtime.h>
#include <hip/hip_bf16.h>
#include <cstdint>

#define NB 16
#define CI 256
#define CO 256
#define HH 64
#define WW 64
#define CC 512
#define HP 66
#define WP 66

typedef short short8 __attribute__((ext_vector_type(8)));
typedef float floatx4 __attribute__((ext_vector_type(4)));
typedef unsigned int uintx4 __attribute__((ext_vector_type(4)));

__device__ __forceinline__ void g2lds16(const void* g, void* l) {
  __builtin_amdgcn_global_load_lds((const __attribute__((address_space(1))) void*)g,
                                   (__attribute__((address_space(3))) void*)l, 16, 0, 0);
}

// Fully-drained barrier: do not trust compiler-inserted waitcnt placement.
#define FULL_SYNC() do {                                              \
    asm volatile("s_waitcnt vmcnt(0) lgkmcnt(0)" ::: "memory");       \
    __builtin_amdgcn_sched_barrier(0);                                \
    __syncthreads();                                                  \
    __builtin_amdgcn_sched_barrier(0);                                \
  } while (0)

// ---------------- zero the padded halo of Xs ----------------
__global__ void k_zero_halo(__hip_bfloat16* __restrict__ Xs) {
  int gid = blockIdx.x * 256 + threadIdx.x;
  int job = gid >> 5;          // halo pixel job
  int unit = gid & 31;         // 16B unit within the 512B pixel row
  int b = job / 260;
  int p = job % 260;
  if (b >= NB) return;
  int hp, wp;
  if (p < 66)       { hp = 0;       wp = p; }
  else if (p < 132) { hp = 65;      wp = p - 66; }
  else if (p < 196) { hp = p - 131; wp = 0; }
  else              { hp = p - 195; wp = 65; }
  uintx4 z = {0u, 0u, 0u, 0u};
  *reinterpret_cast<uintx4*>(Xs + ((((size_t)b * HP + hp) * WP + wp) * CI + unit * 8)) = z;
}

// ---------------- MLP layer: out[b][j] = act(sum_k in[b][k]*w[j][k] + bias[j]) ----------------
template<int KD, int N, bool SILU, bool PLUSONE>
__global__ void k_mlp(const float* __restrict__ in, const float* __restrict__ w,
                      const float* __restrict__ bias, float* __restrict__ out) {
  __shared__ float sin_[KD];
  int b = blockIdx.x;
  for (int k = threadIdx.x; k < KD; k += blockDim.x) sin_[k] = in[b * KD + k];
  __syncthreads();
  int j = threadIdx.x;
  float acc = bias[j];
  const float* wr = w + (size_t)j * KD;
  for (int k = 0; k < KD; k += 4) {
    acc += sin_[k] * wr[k] + sin_[k + 1] * wr[k + 1]
         + sin_[k + 2] * wr[k + 2] + sin_[k + 3] * wr[k + 3];
  }
  if (SILU) acc = acc / (1.0f + __expf(-acc));
  if (PLUSONE) acc += 1.0f;
  out[b * N + j] = acc;
}

// ---------------- weight repack fp32 [O][I][3][3] -> bf16 Wt[t][o][i]; wsq[o][i]=sum_t w^2 ----------------
__global__ void k_repack(const float* __restrict__ cw, __hip_bfloat16* __restrict__ Wt,
                         float* __restrict__ wsq) {
  int gid = blockIdx.x * 256 + threadIdx.x;   // gid = o*CI + i
  if (gid >= CO * CI) return;
  const float* p = cw + (size_t)gid * 9;
  float s = 0.0f;
#pragma unroll
  for (int t = 0; t < 9; ++t) {
    float v = p[t];
    s += v * v;
    Wt[(size_t)t * CO * CI + gid] = __float2bfloat16(v);
  }
  wsq[gid] = s;
}

// ---------------- demod[b][o] = rsqrt(sum_i wsq[o][i]*scale[b][i]^2 + 1e-8) ----------------
__global__ void k_demod(const float* __restrict__ wsq, const float* __restrict__ scale,
                        float* __restrict__ demod) {
  __shared__ float s2[CI];
  int b = blockIdx.x;
  int o = threadIdx.x;
  float sv = scale[b * CI + o];
  s2[o] = sv * sv;
  __syncthreads();
  float acc = 0.0f;
  const float* wr = wsq + (size_t)o * CI;
  for (int i = 0; i < CI; i += 4)
    acc += wr[i] * s2[i] + wr[i + 1] * s2[i + 1] + wr[i + 2] * s2[i + 2] + wr[i + 3] * s2[i + 3];
  demod[b * CO + o] = rsqrtf(acc + 1e-8f);
}

// ---------------- X (NCHW fp32) * scale -> Xs (padded NHWC bf16) via LDS transpose ----------------
__global__ void k_scalex(const float* __restrict__ X, const float* __restrict__ scale,
                         __hip_bfloat16* __restrict__ Xs) {
  __shared__ float tile[64][65];
  __shared__ float ssc[64];
  int bid = blockIdx.x;                 // grid = NB * 64(h) * 4(ichunk)
  int b = bid >> 8;
  int rem = bid & 255;
  int h = rem >> 2;
  int i0 = (rem & 3) * 64;
  int t = threadIdx.x;
  int w = t & 63;
  int ii0 = t >> 6;                     // 0..3
  if (t < 64) ssc[t] = scale[b * CI + i0 + t];
  const float* src = X + (((size_t)b * CI + i0) * HH + h) * WW;
#pragma unroll
  for (int r = 0; r < 16; ++r) {
    int ii = ii0 * 16 + r;
    tile[ii][w] = src[(size_t)ii * HH * WW + w];
  }
  __syncthreads();
  int u = t & 7;                        // i-group
  int wl = t >> 3;                      // 0..31
#pragma unroll
  for (int iter = 0; iter < 2; ++iter) {
    int w2 = wl + iter * 32;
    union { unsigned short us[8]; uintx4 v; } pk;
#pragma unroll
    for (int j = 0; j < 8; ++j) {
      int ii = u * 8 + j;
      float v = tile[ii][w2] * ssc[ii];
      __hip_bfloat16 hb = __float2bfloat16(v);
      pk.us[j] = *reinterpret_cast<unsigned short*>(&hb);
    }
    *reinterpret_cast<uintx4*>(Xs + ((((size_t)b * HP + (h + 1)) * WP + (w2 + 1)) * CI + i0 + u * 8)) = pk.v;
  }
}

// ---------------- main conv: implicit GEMM, out[o][p] = sum_{tap,i} Wt[tap][o][i]*Xs[i][p_shift] ----------------
// tile: BM=128 (o), BN=128 (2 out rows x 64 cols), 512 threads = 8 waves (2 o-sub x 4 pixel-quarters)
// LDS: X-tile [4 rows x 66 cols][64 i] bf16 = 33792 B ; A-tile double-buffered 2 x [128 o][64 i] bf16 = 2x16384 B
__global__ __launch_bounds__(512, 4)
void k_conv(const __hip_bfloat16* __restrict__ Xs, const __hip_bfloat16* __restrict__ Wt,
            const float* __restrict__ demod, float* __restrict__ out) {
  __shared__ __align__(16) char lds[33792 + 2 * 16384];
  char* sX  = lds;
  char* sA0 = lds + 33792;

  int bid = blockIdx.x;                 // 1024 blocks
  int b = bid >> 6;
  int rem = bid & 63;
  int ht = rem >> 1;                    // 0..31
  int ob = rem & 1;
  int h0 = ht * 2;
  int o0 = ob * 128;

  int tid = threadIdx.x;
  int wv = tid >> 6;                    // 0..7
  int lane = tid & 63;
  int lhi = lane >> 4;                  // 0..3
  int llo = lane & 15;                  // 0..15
  int wo = wv >> 2;                     // 0..1
  int wq = wv & 3;                      // 0..3
  int r = wq >> 1;                      // local out row 0..1
  int c0 = (wq & 1) * 32;               // col base 0/32

  floatx4 acc[4][2];
#pragma unroll
  for (int m = 0; m < 4; ++m)
#pragma unroll
    for (int n = 0; n < 2; ++n) acc[m][n] = (floatx4){0.f, 0.f, 0.f, 0.f};

  int row_a[4], ra7[4];
#pragma unroll
  for (int m = 0; m < 4; ++m) { row_a[m] = wo * 64 + m * 16 + llo; ra7[m] = row_a[m] & 7; }

  const __hip_bfloat16* xs_img = Xs + (size_t)b * HP * WP * CI;

  for (int ic = 0; ic < 4; ++ic) {
    // ---- stage X tile: 33 KB-blocks of 1KB (64 lanes x 16B), swizzled source ----
    for (int j = wv; j < 33; j += 8) {
      int u = j * 64 + lane;
      int row = u >> 3;                 // tile pixel-row 0..263 = lr*66 + wp
      int slot = lane & 7;
      int lr = row / 66;
      int wp = row - lr * 66;
      int isel = ic * 64 + ((slot ^ (row & 7)) << 3);
      const __hip_bfloat16* src = xs_img + (((size_t)(h0 + lr) * WP + wp) * CI + isel);
      g2lds16(src, sX + j * 1024);
    }
    for (int t = 0; t < 9; ++t) {
      int kh = t / 3;
      int kw = t - kh * 3;
      char* sA = sA0 + (t & 1) * 16384;   // ping-pong A buffer: no same-buffer WAR window
      // ---- stage A tile (16 KB): wave handles blocks wv, wv+8 ----
      const __hip_bfloat16* wbase = Wt + (size_t)t * CO * CI + (size_t)o0 * CI + ic * 64;
#pragma unroll
      for (int jj = 0; jj < 2; ++jj) {
        int j = wv + jj * 8;
        int row = j * 8 + (lane >> 3);  // o-local 0..127
        int slot = lane & 7;
        int isel = (slot ^ (row & 7)) << 3;
        g2lds16(wbase + (size_t)row * CI + isel, sA + j * 1024);
      }
      FULL_SYNC();
#pragma unroll
      for (int k32 = 0; k32 < 2; ++k32) {
        short8 af[4], bq[2];
#pragma unroll
        for (int m = 0; m < 4; ++m) {
          int addr = row_a[m] * 128 + (((k32 * 4 + lhi) ^ ra7[m]) << 4);
          af[m] = *reinterpret_cast<const short8*>(sA + addr);
        }
#pragma unroll
        for (int n = 0; n < 2; ++n) {
          int tr = (r + kh) * 66 + c0 + n * 16 + llo + kw;
          int addr = tr * 128 + (((k32 * 4 + lhi) ^ (tr & 7)) << 4);
          bq[n] = *reinterpret_cast<const short8*>(sX + addr);
        }
#pragma unroll
        for (int m = 0; m < 4; ++m)
#pragma unroll
          for (int n = 0; n < 2; ++n)
            acc[m][n] = __builtin_amdgcn_mfma_f32_16x16x32_bf16(af[m], bq[n], acc[m][n], 0, 0, 0);
      }
      FULL_SYNC();
    }
  }

  // ---- epilogue: multiply by demod, store fp32 NCHW ----
  const float* dmrow = demod + b * CO + o0 + wo * 64;
  float* obase = out + (((size_t)b * CO + o0 + wo * 64) * HH + (h0 + r)) * WW;
#pragma unroll
  for (int m = 0; m < 4; ++m) {
#pragma unroll
    for (int j = 0; j < 4; ++j) {
      int o_off = m * 16 + lhi * 4 + j;
      float dm = dmrow[o_off];
#pragma unroll
      for (int n = 0; n < 2; ++n) {
        int w = c0 + n * 16 + llo;
        obase[(size_t)o_off * HH * WW + w] = acc[m][n][j] * dm;
      }
    }
  }
}

extern "C" void kernel_launch(void* const* d_in, const int* in_sizes, int n_in,
                              void* d_out, int out_size, void* d_ws, size_t ws_size,
                              hipStream_t stream) {
  const float* X      = (const float*)d_in[0];
  const float* cond_v = (const float*)d_in[1];
  const float* conv_w = (const float*)d_in[2];
  const float* w0     = (const float*)d_in[3];
  const float* b0     = (const float*)d_in[4];
  const float* w1     = (const float*)d_in[5];
  const float* b1     = (const float*)d_in[6];
  const float* w_out  = (const float*)d_in[7];
  const float* b_out  = (const float*)d_in[8];
  float* out = (float*)d_out;

  char* ws = (char*)d_ws;
  const size_t XS_BYTES  = (size_t)NB * HP * WP * CI * 2;          // 35,684,352
  const size_t WT_BYTES  = (size_t)9 * CO * CI * 2;                // 1,179,648
  const size_t WSQ_BYTES = (size_t)CO * CI * 4;                    // 262,144
  __hip_bfloat16* Xs = (__hip_bfloat16*)ws;
  __hip_bfloat16* Wt = (__hip_bfloat16*)(ws + XS_BYTES);
  float* wsq   = (float*)(ws + XS_BYTES + WT_BYTES);
  float* h0b   = (float*)(ws + XS_BYTES + WT_BYTES + WSQ_BYTES);
  float* h1b   = h0b + NB * CC;
  float* scale = h1b + NB * CC;
  float* demod = scale + NB * CI;

  // halo zero: 16*260 pixel jobs * 32 units = 133120 threads
  k_zero_halo<<<520, 256, 0, stream>>>(Xs);
  // weight repack + squared sums
  k_repack<<<(CO * CI) / 256, 256, 0, stream>>>(conv_w, Wt, wsq);
  // cond MLP
  k_mlp<CC, CC, true, false><<<NB, CC, 0, stream>>>(cond_v, w0, b0, h0b);
  k_mlp<CC, CC, true, false><<<NB, CC, 0, stream>>>(h0b, w1, b1, h1b);
  k_mlp<CC, CI, false, true><<<NB, CI, 0, stream>>>(h1b, w_out, b_out, scale);
  // demod
  k_demod<<<NB, CO, 0, stream>>>(wsq, scale, demod);
  // scaled, padded, NHWC bf16 input
  k_scalex<<<NB * 64 * 4, 256, 0, stream>>>(X, scale, Xs);
  // main conv
  k_conv<<<NB * 32 * 2, 512, 0, stream>>>(Xs, Wt, demod, out);
}

// Round 3
// 139.180 us; speedup vs baseline: 1.3553x; 1.3553x over previous
//
#include <hip/hip_runtime.h>
#include <hip/hip_bf16.h>
#include <cstdint>

#define NB 16
#define CI 256
#define CO 256
#define HH 64
#define WW 64
#define CC 512
#define HP 66
#define WP 66

typedef short short8 __attribute__((ext_vector_type(8)));
typedef float floatx4 __attribute__((ext_vector_type(4)));
typedef unsigned int uintx4 __attribute__((ext_vector_type(4)));

__device__ __forceinline__ void g2lds16(const void* g, void* l) {
  __builtin_amdgcn_global_load_lds((const __attribute__((address_space(1))) void*)g,
                                   (__attribute__((address_space(3))) void*)l, 16, 0, 0);
}

// counted-vmcnt + raw barrier primitives (m201-style; __syncthreads would drain vmcnt(0))
#define ASM_VMCNT0() do { asm volatile("s_waitcnt vmcnt(0)" ::: "memory"); \
                          __builtin_amdgcn_sched_barrier(0); } while (0)
#define ASM_VMCNT2() do { asm volatile("s_waitcnt vmcnt(2)" ::: "memory"); \
                          __builtin_amdgcn_sched_barrier(0); } while (0)
#define RAW_BAR() do { __builtin_amdgcn_sched_barrier(0);  \
                       __builtin_amdgcn_s_barrier();       \
                       __builtin_amdgcn_sched_barrier(0); } while (0)

// ---------------- zero the padded halo of Xs ----------------
__global__ void k_zero_halo(__hip_bfloat16* __restrict__ Xs) {
  int gid = blockIdx.x * 256 + threadIdx.x;
  int job = gid >> 5;          // halo pixel job
  int unit = gid & 31;         // 16B unit within the 512B pixel row
  int b = job / 260;
  int p = job % 260;
  if (b >= NB) return;
  int hp, wp;
  if (p < 66)       { hp = 0;       wp = p; }
  else if (p < 132) { hp = 65;      wp = p - 66; }
  else if (p < 196) { hp = p - 131; wp = 0; }
  else              { hp = p - 195; wp = 65; }
  uintx4 z = {0u, 0u, 0u, 0u};
  *reinterpret_cast<uintx4*>(Xs + ((((size_t)b * HP + hp) * WP + wp) * CI + unit * 8)) = z;
}

// ---------------- MLP layer: out[b][j] = act(sum_k in[b][k]*w[j][k] + bias[j]) ----------------
// grid = NB * (N/BJ) blocks of BJ threads; float4 weight streams.
template<int KD, int N, bool SILU, bool PLUSONE, int BJ>
__global__ void k_mlp(const float* __restrict__ in, const float* __restrict__ w,
                      const float* __restrict__ bias, float* __restrict__ out) {
  __shared__ float4 sin4[KD / 4];
  const int nb = N / BJ;
  int b = blockIdx.x / nb;
  int j = (blockIdx.x % nb) * BJ + threadIdx.x;
  const float4* in4 = reinterpret_cast<const float4*>(in + (size_t)b * KD);
  for (int k = threadIdx.x; k < KD / 4; k += BJ) sin4[k] = in4[k];
  __syncthreads();
  float acc = bias[j];
  const float4* wr = reinterpret_cast<const float4*>(w + (size_t)j * KD);
#pragma unroll 8
  for (int kk = 0; kk < KD / 4; ++kk) {
    float4 wv = wr[kk];
    float4 sv = sin4[kk];
    acc += wv.x * sv.x + wv.y * sv.y + wv.z * sv.z + wv.w * sv.w;
  }
  if (SILU) acc = acc / (1.0f + __expf(-acc));
  if (PLUSONE) acc += 1.0f;
  out[(size_t)b * N + j] = acc;
}

// ---------------- weight repack fp32 [O][I][3][3] -> bf16 Wt[t][o][i]; wsq[o][i]=sum_t w^2 ----------------
__global__ void k_repack(const float* __restrict__ cw, __hip_bfloat16* __restrict__ Wt,
                         float* __restrict__ wsq) {
  int gid = blockIdx.x * 256 + threadIdx.x;   // gid = o*CI + i
  if (gid >= CO * CI) return;
  const float* p = cw + (size_t)gid * 9;
  float s = 0.0f;
#pragma unroll
  for (int t = 0; t < 9; ++t) {
    float v = p[t];
    s += v * v;
    Wt[(size_t)t * CO * CI + gid] = __float2bfloat16(v);
  }
  wsq[gid] = s;
}

// ---------------- demod[b][o] = rsqrt(sum_i wsq[o][i]*scale[b][i]^2 + 1e-8) ----------------
__global__ void k_demod(const float* __restrict__ wsq, const float* __restrict__ scale,
                        float* __restrict__ demod) {
  __shared__ float s2[CI];
  int b = blockIdx.x;
  int o = threadIdx.x;
  float sv = scale[b * CI + o];
  s2[o] = sv * sv;
  __syncthreads();
  float acc = 0.0f;
  const float4* wr = reinterpret_cast<const float4*>(wsq + (size_t)o * CI);
  const float4* s4 = reinterpret_cast<const float4*>(s2);
#pragma unroll 8
  for (int i = 0; i < CI / 4; ++i) {
    float4 wv = wr[i];
    float4 sq = s4[i];
    acc += wv.x * sq.x + wv.y * sq.y + wv.z * sq.z + wv.w * sq.w;
  }
  demod[b * CO + o] = rsqrtf(acc + 1e-8f);
}

// ---------------- X (NCHW fp32) * scale -> Xs (padded NHWC bf16) via LDS transpose ----------------
__global__ void k_scalex(const float* __restrict__ X, const float* __restrict__ scale,
                         __hip_bfloat16* __restrict__ Xs) {
  __shared__ float tile[64][68];        // pitch 68: float4-aligned, transpose reads 2-way (free)
  __shared__ float ssc[64];
  int bid = blockIdx.x;                 // grid = NB * 64(h) * 4(ichunk)
  int b = bid >> 8;
  int rem = bid & 255;
  int h = rem >> 2;
  int i0 = (rem & 3) * 64;
  int t = threadIdx.x;
  if (t < 64) ssc[t] = scale[b * CI + i0 + t];
  const float* src = X + (((size_t)b * CI + i0) * HH + h) * WW;
  int ii_base = t >> 4;                 // 0..15
  int w4 = (t & 15) * 4;
#pragma unroll
  for (int r2 = 0; r2 < 4; ++r2) {
    int ii = r2 * 16 + ii_base;
    *reinterpret_cast<float4*>(&tile[ii][w4]) =
        *reinterpret_cast<const float4*>(src + (size_t)ii * HH * WW + w4);
  }
  __syncthreads();
  int u = t & 7;                        // i-group
  int wl = t >> 3;                      // 0..31
#pragma unroll
  for (int iter = 0; iter < 2; ++iter) {
    int w2 = wl + iter * 32;
    union { unsigned short us[8]; uintx4 v; } pk;
#pragma unroll
    for (int j = 0; j < 8; ++j) {
      int ii = u * 8 + j;
      float v = tile[ii][w2] * ssc[ii];
      __hip_bfloat16 hb = __float2bfloat16(v);
      pk.us[j] = *reinterpret_cast<unsigned short*>(&hb);
    }
    *reinterpret_cast<uintx4*>(Xs + ((((size_t)b * HP + (h + 1)) * WP + (w2 + 1)) * CI + i0 + u * 8)) = pk.v;
  }
}

// ---------------- main conv: implicit GEMM, out[o][p] = sum_{tap,i} Wt[tap][o][i]*Xs[i][p_shift] ----------------
// tile: BM=128 (o), BN=128 (2 out rows x 64 cols), 512 threads = 8 waves (2 o-sub x 4 pixel-quarters)
// LDS: X-tile [4 rows x 66 cols][64 i] bf16 = 33792 B ; A ping-pong 2 x [128 o][64 i] bf16 = 2x16384 B
// Sync: A(t+1) prefetched before barrier1(t); counted s_waitcnt vmcnt(2) (A(t+1) stays in flight).
// Safety: stage(t+1) targets buf[(t+1)&1], last read at tap t-1 — all waves passed barrier2(t-1).
__global__ __launch_bounds__(512, 4)
void k_conv(const __hip_bfloat16* __restrict__ Xs, const __hip_bfloat16* __restrict__ Wt,
            const float* __restrict__ demod, float* __restrict__ out) {
  __shared__ __align__(16) char lds[33792 + 2 * 16384];
  char* sX  = lds;
  char* sA0 = lds + 33792;

  int bid = blockIdx.x;                 // 1024 blocks
  int b = bid >> 6;
  int rem = bid & 63;
  int ht = rem >> 1;                    // 0..31
  int ob = rem & 1;
  int h0 = ht * 2;
  int o0 = ob * 128;

  int tid = threadIdx.x;
  int wv = tid >> 6;                    // 0..7
  int lane = tid & 63;
  int lhi = lane >> 4;                  // 0..3
  int llo = lane & 15;                  // 0..15
  int wo = wv >> 2;                     // 0..1
  int wq = wv & 3;                      // 0..3
  int r = wq >> 1;                      // local out row 0..1
  int c0 = (wq & 1) * 32;               // col base 0/32

  floatx4 acc[4][2];
#pragma unroll
  for (int m = 0; m < 4; ++m)
#pragma unroll
    for (int n = 0; n < 2; ++n) acc[m][n] = (floatx4){0.f, 0.f, 0.f, 0.f};

  int row_a[4], ra7[4];
#pragma unroll
  for (int m = 0; m < 4; ++m) { row_a[m] = wo * 64 + m * 16 + llo; ra7[m] = row_a[m] & 7; }

  const __hip_bfloat16* xs_img = Xs + (size_t)b * HP * WP * CI;

  for (int ic = 0; ic < 4; ++ic) {
    // ---- stage X tile: 33 blocks of 1KB (64 lanes x 16B), swizzled source; 4-5 loads/wave ----
    for (int j = wv; j < 33; j += 8) {
      int u = j * 64 + lane;
      int row = u >> 3;                 // tile pixel-row 0..263 = lr*66 + wp
      int slot = lane & 7;
      int lr = row / 66;
      int wp = row - lr * 66;
      int isel = ic * 64 + ((slot ^ (row & 7)) << 3);
      const __hip_bfloat16* src = xs_img + (((size_t)(h0 + lr) * WP + wp) * CI + isel);
      g2lds16(src, sX + j * 1024);
    }
    // ---- stage A(tap 0) into buf0; full drain (X loads are wave-nonuniform) ----
    {
      const __hip_bfloat16* wbase = Wt + (size_t)o0 * CI + ic * 64;   // t=0
#pragma unroll
      for (int jj = 0; jj < 2; ++jj) {
        int j = wv + jj * 8;
        int row = j * 8 + (lane >> 3);
        int slot = lane & 7;
        int isel = (slot ^ (row & 7)) << 3;
        g2lds16(wbase + (size_t)row * CI + isel, sA0 + j * 1024);
      }
    }
    ASM_VMCNT0();
    RAW_BAR();

    for (int t = 0; t < 9; ++t) {
      char* sA = sA0 + (t & 1) * 16384;
      // ---- prefetch A(t+1) into the other buffer; counted wait: A(t)'s 2 loads are the oldest ----
      if (t < 8) {
        const __hip_bfloat16* wbase = Wt + (size_t)(t + 1) * CO * CI + (size_t)o0 * CI + ic * 64;
        char* dst = sA0 + ((t + 1) & 1) * 16384;
#pragma unroll
        for (int jj = 0; jj < 2; ++jj) {
          int j = wv + jj * 8;
          int row = j * 8 + (lane >> 3);
          int slot = lane & 7;
          int isel = (slot ^ (row & 7)) << 3;
          g2lds16(wbase + (size_t)row * CI + isel, dst + j * 1024);
        }
        ASM_VMCNT2();
      } else {
        ASM_VMCNT0();
      }
      RAW_BAR();                        // barrier1: everyone's A(t) landed

      int kh = t / 3;
      int kw = t - kh * 3;
#pragma unroll
      for (int k32 = 0; k32 < 2; ++k32) {
        short8 af[4], bq[2];
#pragma unroll
        for (int m = 0; m < 4; ++m) {
          int addr = row_a[m] * 128 + (((k32 * 4 + lhi) ^ ra7[m]) << 4);
          af[m] = *reinterpret_cast<const short8*>(sA + addr);
        }
#pragma unroll
        for (int n = 0; n < 2; ++n) {
          int tr = (r + kh) * 66 + c0 + n * 16 + llo + kw;
          int addr = tr * 128 + (((k32 * 4 + lhi) ^ (tr & 7)) << 4);
          bq[n] = *reinterpret_cast<const short8*>(sX + addr);
        }
#pragma unroll
        for (int m = 0; m < 4; ++m)
#pragma unroll
          for (int n = 0; n < 2; ++n)
            acc[m][n] = __builtin_amdgcn_mfma_f32_16x16x32_bf16(af[m], bq[n], acc[m][n], 0, 0, 0);
      }
      RAW_BAR();                        // barrier2: reads(t) done everywhere -> next stage may overwrite
    }
  }

  // ---- epilogue: multiply by demod, store fp32 NCHW ----
  const float* dmrow = demod + b * CO + o0 + wo * 64;
  float* obase = out + (((size_t)b * CO + o0 + wo * 64) * HH + (h0 + r)) * WW;
#pragma unroll
  for (int m = 0; m < 4; ++m) {
#pragma unroll
    for (int j = 0; j < 4; ++j) {
      int o_off = m * 16 + lhi * 4 + j;
      float dm = dmrow[o_off];
#pragma unroll
      for (int n = 0; n < 2; ++n) {
        int w = c0 + n * 16 + llo;
        obase[(size_t)o_off * HH * WW + w] = acc[m][n][j] * dm;
      }
    }
  }
}

extern "C" void kernel_launch(void* const* d_in, const int* in_sizes, int n_in,
                              void* d_out, int out_size, void* d_ws, size_t ws_size,
                              hipStream_t stream) {
  const float* X      = (const float*)d_in[0];
  const float* cond_v = (const float*)d_in[1];
  const float* conv_w = (const float*)d_in[2];
  const float* w0     = (const float*)d_in[3];
  const float* b0     = (const float*)d_in[4];
  const float* w1     = (const float*)d_in[5];
  const float* b1     = (const float*)d_in[6];
  const float* w_out  = (const float*)d_in[7];
  const float* b_out  = (const float*)d_in[8];
  float* out = (float*)d_out;

  char* ws = (char*)d_ws;
  const size_t XS_BYTES  = (size_t)NB * HP * WP * CI * 2;          // 35,684,352
  const size_t WT_BYTES  = (size_t)9 * CO * CI * 2;                // 1,179,648
  const size_t WSQ_BYTES = (size_t)CO * CI * 4;                    // 262,144
  __hip_bfloat16* Xs = (__hip_bfloat16*)ws;
  __hip_bfloat16* Wt = (__hip_bfloat16*)(ws + XS_BYTES);
  float* wsq   = (float*)(ws + XS_BYTES + WT_BYTES);
  float* h0b   = (float*)(ws + XS_BYTES + WT_BYTES + WSQ_BYTES);
  float* h1b   = h0b + NB * CC;
  float* scale = h1b + NB * CC;
  float* demod = scale + NB * CI;

  // halo zero: 16*260 pixel jobs * 32 units = 133120 threads
  k_zero_halo<<<520, 256, 0, stream>>>(Xs);
  // weight repack + squared sums
  k_repack<<<(CO * CI) / 256, 256, 0, stream>>>(conv_w, Wt, wsq);
  // cond MLP (128-thread blocks, N/128 j-tiles per batch for parallelism)
  k_mlp<CC, CC, true, false, 128><<<NB * (CC / 128), 128, 0, stream>>>(cond_v, w0, b0, h0b);
  k_mlp<CC, CC, true, false, 128><<<NB * (CC / 128), 128, 0, stream>>>(h0b, w1, b1, h1b);
  k_mlp<CC, CI, false, true, 128><<<NB * (CI / 128), 128, 0, stream>>>(h1b, w_out, b_out, scale);
  // demod
  k_demod<<<NB, CO, 0, stream>>>(wsq, scale, demod);
  // scaled, padded, NHWC bf16 input
  k_scalex<<<NB * 64 * 4, 256, 0, stream>>>(X, scale, Xs);
  // main conv
  k_conv<<<NB * 32 * 2, 512, 0, stream>>>(Xs, Wt, demod, out);
}

// Round 4
// 135.937 us; speedup vs baseline: 1.3876x; 1.0239x over previous
//
#include <hip/hip_runtime.h>
#include <hip/hip_bf16.h>
#include <cstdint>

#define NB 16
#define CI 256
#define CO 256
#define HH 64
#define WW 64
#define CC 512
#define HP 66
#define WP 66

typedef short short8 __attribute__((ext_vector_type(8)));
typedef float floatx4 __attribute__((ext_vector_type(4)));
typedef unsigned int uintx4 __attribute__((ext_vector_type(4)));

__device__ __forceinline__ void g2lds16(const void* g, void* l) {
  __builtin_amdgcn_global_load_lds((const __attribute__((address_space(1))) void*)g,
                                   (__attribute__((address_space(3))) void*)l, 16, 0, 0);
}

// counted-vmcnt + raw barrier primitives (__syncthreads would drain vmcnt(0))
#define ASM_VMCNT0() do { asm volatile("s_waitcnt vmcnt(0)" ::: "memory"); \
                          __builtin_amdgcn_sched_barrier(0); } while (0)
#define ASM_VMCNT4() do { asm volatile("s_waitcnt vmcnt(4)" ::: "memory"); \
                          __builtin_amdgcn_sched_barrier(0); } while (0)
#define RAW_BAR() do { __builtin_amdgcn_sched_barrier(0);  \
                       __builtin_amdgcn_s_barrier();       \
                       __builtin_amdgcn_sched_barrier(0); } while (0)

// ---------------- MLP layer: out[b][j] = act(sum_k in[b][k]*w[j][k] + bias[j]) ----------------
template<int KD, int N, bool SILU, bool PLUSONE, int BJ>
__global__ void k_mlp(const float* __restrict__ in, const float* __restrict__ w,
                      const float* __restrict__ bias, float* __restrict__ out) {
  __shared__ float4 sin4[KD / 4];
  const int nb = N / BJ;
  int b = blockIdx.x / nb;
  int j = (blockIdx.x % nb) * BJ + threadIdx.x;
  const float4* in4 = reinterpret_cast<const float4*>(in + (size_t)b * KD);
  for (int k = threadIdx.x; k < KD / 4; k += BJ) sin4[k] = in4[k];
  __syncthreads();
  float acc = bias[j];
  const float4* wr = reinterpret_cast<const float4*>(w + (size_t)j * KD);
#pragma unroll 8
  for (int kk = 0; kk < KD / 4; ++kk) {
    float4 wv = wr[kk];
    float4 sv = sin4[kk];
    acc += wv.x * sv.x + wv.y * sv.y + wv.z * sv.z + wv.w * sv.w;
  }
  if (SILU) acc = acc / (1.0f + __expf(-acc));
  if (PLUSONE) acc += 1.0f;
  out[(size_t)b * N + j] = acc;
}

// ---------------- weight repack fp32 [O][I][3][3] -> bf16 Wt[t][o][i]; wsq[o][i]=sum_t w^2 ----------------
__global__ void k_repack(const float* __restrict__ cw, __hip_bfloat16* __restrict__ Wt,
                         float* __restrict__ wsq) {
  int gid = blockIdx.x * 256 + threadIdx.x;   // gid = o*CI + i
  if (gid >= CO * CI) return;
  const float* p = cw + (size_t)gid * 9;
  float s = 0.0f;
#pragma unroll
  for (int t = 0; t < 9; ++t) {
    float v = p[t];
    s += v * v;
    Wt[(size_t)t * CO * CI + gid] = __float2bfloat16(v);
  }
  wsq[gid] = s;
}

// ---------------- demod[b][o] = rsqrt(sum_i wsq[o][i]*scale[b][i]^2 + 1e-8) ----------------
__global__ void k_demod(const float* __restrict__ wsq, const float* __restrict__ scale,
                        float* __restrict__ demod) {
  __shared__ float s2[CI];
  int b = blockIdx.x;
  int o = threadIdx.x;
  float sv = scale[b * CI + o];
  s2[o] = sv * sv;
  __syncthreads();
  float acc = 0.0f;
  const float4* wr = reinterpret_cast<const float4*>(wsq + (size_t)o * CI);
  const float4* s4 = reinterpret_cast<const float4*>(s2);
#pragma unroll 8
  for (int i = 0; i < CI / 4; ++i) {
    float4 wv = wr[i];
    float4 sq = s4[i];
    acc += wv.x * sq.x + wv.y * sq.y + wv.z * sq.z + wv.w * sq.w;
  }
  demod[b * CO + o] = rsqrtf(acc + 1e-8f);
}

// ---------------- X (NCHW fp32) * scale -> Xs (padded NHWC bf16); halo zeroing fused ----------------
// LDS transpose with float4-granular XOR swizzle keyed on (ii>>3) -> 2-way (free) transpose reads.
__global__ void k_scalex(const float* __restrict__ X, const float* __restrict__ scale,
                         __hip_bfloat16* __restrict__ Xs) {
  __shared__ float tile[64][68];
  __shared__ float ssc[64];
  int bid = blockIdx.x;                 // grid = NB * 64(h) * 4(ichunk)
  int b = bid >> 8;
  int rem = bid & 255;
  int h = rem >> 2;
  int i0 = (rem & 3) * 64;
  int t = threadIdx.x;
  if (t < 64) ssc[t] = scale[b * CI + i0 + t];

  __hip_bfloat16* xs_img = Xs + (size_t)b * HP * WP * CI;
  uintx4 z = {0u, 0u, 0u, 0u};
  // fused halo zero: side columns (px 0 and 65) of this padded row, this ic chunk
  if (t < 16) {
    int px = (t >> 3) * 65;
    int sl = t & 7;
    *reinterpret_cast<uintx4*>(xs_img + (((size_t)(h + 1)) * WP + px) * CI + i0 + sl * 8) = z;
  }
  // top/bottom padded rows, done by h==0 / h==63 blocks for their ic chunk
  if (h == 0) {
    for (int u = t; u < 66 * 8; u += 256) {
      int px = u >> 3, sl = u & 7;
      *reinterpret_cast<uintx4*>(xs_img + ((size_t)px) * CI + i0 + sl * 8) = z;
    }
  }
  if (h == 63) {
    for (int u = t; u < 66 * 8; u += 256) {
      int px = u >> 3, sl = u & 7;
      *reinterpret_cast<uintx4*>(xs_img + ((size_t)65 * WP + px) * CI + i0 + sl * 8) = z;
    }
  }

  const float* src = X + (((size_t)b * CI + i0) * HH + h) * WW;
  int ii_base = t >> 4;                 // 0..3
  int w4 = (t & 15) * 4;
#pragma unroll
  for (int r2 = 0; r2 < 4; ++r2) {
    int ii = r2 * 16 + ii_base;
    int key = ((ii >> 3) & 7) << 2;     // float4-granular XOR key
    *reinterpret_cast<float4*>(&tile[ii][w4 ^ key]) =
        *reinterpret_cast<const float4*>(src + (size_t)ii * HH * WW + w4);
  }
  __syncthreads();
  int u = t & 7;                        // i-group (= ii>>3 of the reads below)
  int wl = t >> 3;                      // 0..31
  int key = u << 2;
#pragma unroll
  for (int iter = 0; iter < 2; ++iter) {
    int w2 = wl + iter * 32;
    union { unsigned short us[8]; uintx4 v; } pk;
#pragma unroll
    for (int j = 0; j < 8; ++j) {
      int ii = u * 8 + j;
      float v = tile[ii][w2 ^ key] * ssc[ii];
      __hip_bfloat16 hb = __float2bfloat16(v);
      pk.us[j] = *reinterpret_cast<unsigned short*>(&hb);
    }
    *reinterpret_cast<uintx4*>(xs_img + (((size_t)(h + 1)) * WP + (w2 + 1)) * CI + i0 + u * 8) = pk.v;
  }
}

// ---------------- main conv: implicit GEMM ----------------
// tile: BM=256 (all o) x BN=256 px (4 out rows x 64 cols); 8 waves = 4 o-groups x 2 px-groups.
// Per wave: 64 o x 128 px = acc[4][8]; per k32: 4 af + 8 bq reads -> 32 MFMA (LDS/MFMA pipes balanced).
// LDS: X [6 stripes][72 px][64 i] bf16 = 55296 B (cols 66-71 clamp-dup, never read);
//      A ping-pong 2 x [256 o][64 i] = 65536 B. Total 120832 -> 1 block/CU.
__global__ __launch_bounds__(512, 2)
void k_conv(const __hip_bfloat16* __restrict__ Xs, const __hip_bfloat16* __restrict__ Wt,
            const float* __restrict__ demod, float* __restrict__ out) {
  __shared__ __align__(16) char lds[55296 + 2 * 32768];
  char* sX  = lds;
  char* sA0 = lds + 55296;

  // bijective XCD swizzle: 256 blocks, 32/XCD -> 2 images per XCD L2
  int wg = (blockIdx.x & 7) * 32 + (blockIdx.x >> 3);
  int b = wg >> 4;
  int ht = wg & 15;
  int h0 = ht * 4;                      // 4 output rows per block

  int tid = threadIdx.x;
  int wv = tid >> 6;                    // 0..7
  int lane = tid & 63;
  int lhi = lane >> 4;                  // 0..3
  int llo = lane & 15;                  // 0..15
  int wo = wv >> 1;                     // 0..3  (o-group)
  int wpx = wv & 1;                     // 0..1  (px-group: 2 out rows)

  floatx4 acc[4][8];
#pragma unroll
  for (int m = 0; m < 4; ++m)
#pragma unroll
    for (int n = 0; n < 8; ++n) acc[m][n] = (floatx4){0.f, 0.f, 0.f, 0.f};

  int row_a[4], ra7[4];
#pragma unroll
  for (int m = 0; m < 4; ++m) { row_a[m] = wo * 64 + m * 16 + llo; ra7[m] = row_a[m] & 7; }

  const __hip_bfloat16* xs_img = Xs + (size_t)b * HP * WP * CI;

  for (int ic = 0; ic < 4; ++ic) {
    // ---- stage X tile: 54 blocks of 1KB; source-XOR swizzle; cols 66-71 clamped ----
    for (int j = wv; j < 54; j += 8) {
      int u = j * 64 + lane;
      int pr = u >> 3;                  // LDS pixel-row 0..431 = lr*72 + wp
      int slot = lane & 7;
      int lr = pr / 72;
      int wp = pr - lr * 72;
      if (wp > 65) wp = 65;             // duplicate px65 into pad cols (never read)
      int isel = ic * 64 + ((slot ^ (pr & 7)) << 3);
      const __hip_bfloat16* src = xs_img + (((size_t)(h0 + lr) * WP + wp) * CI + isel);
      g2lds16(src, sX + j * 1024);
    }
    // ---- stage A(tap 0) into buf0 ----
    {
      const __hip_bfloat16* wbase = Wt + ic * 64;   // t=0, o0=0
#pragma unroll
      for (int jj = 0; jj < 4; ++jj) {
        int j = wv * 4 + jj;
        int row = j * 8 + (lane >> 3);
        int slot = lane & 7;
        int isel = (slot ^ (row & 7)) << 3;
        g2lds16(wbase + (size_t)row * CI + isel, sA0 + j * 1024);
      }
    }
    ASM_VMCNT0();
    RAW_BAR();

    for (int t = 0; t < 9; ++t) {
      char* sA = sA0 + (t & 1) * 32768;
      // ---- prefetch A(t+1) into the other buffer; counted wait (A(t)'s 4 loads are oldest) ----
      if (t < 8) {
        const __hip_bfloat16* wbase = Wt + (size_t)(t + 1) * CO * CI + ic * 64;
        char* dst = sA0 + ((t + 1) & 1) * 32768;
#pragma unroll
        for (int jj = 0; jj < 4; ++jj) {
          int j = wv * 4 + jj;
          int row = j * 8 + (lane >> 3);
          int slot = lane & 7;
          int isel = (slot ^ (row & 7)) << 3;
          g2lds16(wbase + (size_t)row * CI + isel, dst + j * 1024);
        }
        ASM_VMCNT4();
      } else {
        ASM_VMCNT0();
      }
      RAW_BAR();                        // barrier1: A(t) landed everywhere

      int kh = t / 3;
      int kw = t - kh * 3;
#pragma unroll
      for (int k32 = 0; k32 < 2; ++k32) {
        int kidx = k32 * 4 + lhi;
        short8 af[4];
#pragma unroll
        for (int m = 0; m < 4; ++m) {
          int addr = row_a[m] * 128 + ((kidx ^ ra7[m]) << 4);
          af[m] = *reinterpret_cast<const short8*>(sA + addr);
        }
#pragma unroll
        for (int n = 0; n < 8; ++n) {
          int stripe = wpx * 2 + (n >> 2) + kh;          // 0..5
          int px = (n & 3) * 16 + llo + kw;              // 0..65
          int prl = stripe * 72 + px;
          int addr = prl * 128 + ((kidx ^ (prl & 7)) << 4);
          short8 bq = *reinterpret_cast<const short8*>(sX + addr);
#pragma unroll
          for (int m = 0; m < 4; ++m)
            acc[m][n] = __builtin_amdgcn_mfma_f32_16x16x32_bf16(af[m], bq, acc[m][n], 0, 0, 0);
        }
      }
      RAW_BAR();                        // barrier2: reads(t) done -> next stage may overwrite
    }
  }

  // ---- epilogue: demod multiply, fp32 NCHW stores ----
#pragma unroll
  for (int m = 0; m < 4; ++m) {
    int obase_o = wo * 64 + m * 16 + lhi * 4;
    float4 dmv = *reinterpret_cast<const float4*>(demod + (size_t)b * CO + obase_o);
#pragma unroll
    for (int j = 0; j < 4; ++j) {
      int o = obase_o + j;
      float dm = (j == 0) ? dmv.x : (j == 1) ? dmv.y : (j == 2) ? dmv.z : dmv.w;
      float* orow = out + (((size_t)b * CO + o) * HH + h0) * WW;
#pragma unroll
      for (int n = 0; n < 8; ++n) {
        int row = wpx * 2 + (n >> 2);
        int col = (n & 3) * 16 + llo;
        orow[(size_t)row * WW + col] = acc[m][n][j] * dm;
      }
    }
  }
}

extern "C" void kernel_launch(void* const* d_in, const int* in_sizes, int n_in,
                              void* d_out, int out_size, void* d_ws, size_t ws_size,
                              hipStream_t stream) {
  const float* X      = (const float*)d_in[0];
  const float* cond_v = (const float*)d_in[1];
  const float* conv_w = (const float*)d_in[2];
  const float* w0     = (const float*)d_in[3];
  const float* b0     = (const float*)d_in[4];
  const float* w1     = (const float*)d_in[5];
  const float* b1     = (const float*)d_in[6];
  const float* w_out  = (const float*)d_in[7];
  const float* b_out  = (const float*)d_in[8];
  float* out = (float*)d_out;

  char* ws = (char*)d_ws;
  const size_t XS_BYTES  = (size_t)NB * HP * WP * CI * 2;
  const size_t WT_BYTES  = (size_t)9 * CO * CI * 2;
  const size_t WSQ_BYTES = (size_t)CO * CI * 4;
  __hip_bfloat16* Xs = (__hip_bfloat16*)ws;
  __hip_bfloat16* Wt = (__hip_bfloat16*)(ws + XS_BYTES);
  float* wsq   = (float*)(ws + XS_BYTES + WT_BYTES);
  float* h0b   = (float*)(ws + XS_BYTES + WT_BYTES + WSQ_BYTES);
  float* h1b   = h0b + NB * CC;
  float* scale = h1b + NB * CC;
  float* demod = scale + NB * CI;

  // weight repack + squared sums
  k_repack<<<(CO * CI) / 256, 256, 0, stream>>>(conv_w, Wt, wsq);
  // cond MLP
  k_mlp<CC, CC, true, false, 128><<<NB * (CC / 128), 128, 0, stream>>>(cond_v, w0, b0, h0b);
  k_mlp<CC, CC, true, false, 128><<<NB * (CC / 128), 128, 0, stream>>>(h0b, w1, b1, h1b);
  k_mlp<CC, CI, false, true, 128><<<NB * (CI / 128), 128, 0, stream>>>(h1b, w_out, b_out, scale);
  // demod
  k_demod<<<NB, CO, 0, stream>>>(wsq, scale, demod);
  // scaled, padded, NHWC bf16 input (halo zeroing fused)
  k_scalex<<<NB * 64 * 4, 256, 0, stream>>>(X, scale, Xs);
  // main conv: 256 blocks, 1 per CU
  k_conv<<<NB * 16, 512, 0, stream>>>(Xs, Wt, demod, out);
}

// Round 5
// 132.738 us; speedup vs baseline: 1.4211x; 1.0241x over previous
//
#include <hip/hip_runtime.h>
#include <hip/hip_bf16.h>
#include <cstdint>

#define NB 16
#define CI 256
#define CO 256
#define HH 64
#define WW 64
#define CC 512
#define HP 66
#define WP 66

typedef short short8 __attribute__((ext_vector_type(8)));
typedef float floatx4 __attribute__((ext_vector_type(4)));
typedef unsigned int uintx4 __attribute__((ext_vector_type(4)));

__device__ __forceinline__ void g2lds16(const void* g, void* l) {
  __builtin_amdgcn_global_load_lds((const __attribute__((address_space(1))) void*)g,
                                   (__attribute__((address_space(3))) void*)l, 16, 0, 0);
}

// counted-vmcnt + raw barrier primitives (__syncthreads would drain vmcnt(0))
#define ASM_VMCNT0() do { asm volatile("s_waitcnt vmcnt(0)" ::: "memory"); \
                          __builtin_amdgcn_sched_barrier(0); } while (0)
#define ASM_VMCNT2() do { asm volatile("s_waitcnt vmcnt(2)" ::: "memory"); \
                          __builtin_amdgcn_sched_barrier(0); } while (0)
#define ASM_VMCNT3() do { asm volatile("s_waitcnt vmcnt(3)" ::: "memory"); \
                          __builtin_amdgcn_sched_barrier(0); } while (0)
#define RAW_BAR() do { __builtin_amdgcn_sched_barrier(0);  \
                       __builtin_amdgcn_s_barrier();       \
                       __builtin_amdgcn_sched_barrier(0); } while (0)

// ---------------- MLP layer: out[b][j] = act(sum_k in[b][k]*w[j][k] + bias[j]) ----------------
template<int KD, int N, bool SILU, bool PLUSONE, int BJ>
__global__ void k_mlp(const float* __restrict__ in, const float* __restrict__ w,
                      const float* __restrict__ bias, float* __restrict__ out) {
  __shared__ float4 sin4[KD / 4];
  const int nb = N / BJ;
  int b = blockIdx.x / nb;
  int j = (blockIdx.x % nb) * BJ + threadIdx.x;
  const float4* in4 = reinterpret_cast<const float4*>(in + (size_t)b * KD);
  for (int k = threadIdx.x; k < KD / 4; k += BJ) sin4[k] = in4[k];
  __syncthreads();
  float acc = bias[j];
  const float4* wr = reinterpret_cast<const float4*>(w + (size_t)j * KD);
#pragma unroll 8
  for (int kk = 0; kk < KD / 4; ++kk) {
    float4 wv = wr[kk];
    float4 sv = sin4[kk];
    acc += wv.x * sv.x + wv.y * sv.y + wv.z * sv.z + wv.w * sv.w;
  }
  if (SILU) acc = acc / (1.0f + __expf(-acc));
  if (PLUSONE) acc += 1.0f;
  out[(size_t)b * N + j] = acc;
}

// ---------------- weight repack fp32 [O][I][3][3] -> bf16 Wt[t][o][i]; wsq[o][i]=sum_t w^2 ----------------
__global__ void k_repack(const float* __restrict__ cw, __hip_bfloat16* __restrict__ Wt,
                         float* __restrict__ wsq) {
  int gid = blockIdx.x * 256 + threadIdx.x;   // gid = o*CI + i
  if (gid >= CO * CI) return;
  const float* p = cw + (size_t)gid * 9;
  float s = 0.0f;
#pragma unroll
  for (int t = 0; t < 9; ++t) {
    float v = p[t];
    s += v * v;
    Wt[(size_t)t * CO * CI + gid] = __float2bfloat16(v);
  }
  wsq[gid] = s;
}

// ---------------- demod[b][o] = rsqrt(sum_i wsq[o][i]*scale[b][i]^2 + 1e-8) ----------------
__global__ void k_demod(const float* __restrict__ wsq, const float* __restrict__ scale,
                        float* __restrict__ demod) {
  __shared__ float s2[CI];
  int b = blockIdx.x;
  int o = threadIdx.x;
  float sv = scale[b * CI + o];
  s2[o] = sv * sv;
  __syncthreads();
  float acc = 0.0f;
  const float4* wr = reinterpret_cast<const float4*>(wsq + (size_t)o * CI);
  const float4* s4 = reinterpret_cast<const float4*>(s2);
#pragma unroll 8
  for (int i = 0; i < CI / 4; ++i) {
    float4 wv = wr[i];
    float4 sq = s4[i];
    acc += wv.x * sq.x + wv.y * sq.y + wv.z * sq.z + wv.w * sq.w;
  }
  demod[b * CO + o] = rsqrtf(acc + 1e-8f);
}

// ---------------- X (NCHW fp32) * scale -> Xs (padded NHWC bf16); halo zeroing fused ----------------
__global__ void k_scalex(const float* __restrict__ X, const float* __restrict__ scale,
                         __hip_bfloat16* __restrict__ Xs) {
  __shared__ float tile[64][68];
  __shared__ float ssc[64];
  int bid = blockIdx.x;                 // grid = NB * 64(h) * 4(ichunk)
  int b = bid >> 8;
  int rem = bid & 255;
  int h = rem >> 2;
  int i0 = (rem & 3) * 64;
  int t = threadIdx.x;
  if (t < 64) ssc[t] = scale[b * CI + i0 + t];

  __hip_bfloat16* xs_img = Xs + (size_t)b * HP * WP * CI;
  uintx4 z = {0u, 0u, 0u, 0u};
  if (t < 16) {
    int px = (t >> 3) * 65;
    int sl = t & 7;
    *reinterpret_cast<uintx4*>(xs_img + (((size_t)(h + 1)) * WP + px) * CI + i0 + sl * 8) = z;
  }
  if (h == 0) {
    for (int u = t; u < 66 * 8; u += 256) {
      int px = u >> 3, sl = u & 7;
      *reinterpret_cast<uintx4*>(xs_img + ((size_t)px) * CI + i0 + sl * 8) = z;
    }
  }
  if (h == 63) {
    for (int u = t; u < 66 * 8; u += 256) {
      int px = u >> 3, sl = u & 7;
      *reinterpret_cast<uintx4*>(xs_img + ((size_t)65 * WP + px) * CI + i0 + sl * 8) = z;
    }
  }

  const float* src = X + (((size_t)b * CI + i0) * HH + h) * WW;
  int ii_base = t >> 4;                 // 0..3
  int w4 = (t & 15) * 4;
#pragma unroll
  for (int r2 = 0; r2 < 4; ++r2) {
    int ii = r2 * 16 + ii_base;
    int key = ((ii >> 3) & 7) << 2;
    *reinterpret_cast<float4*>(&tile[ii][w4 ^ key]) =
        *reinterpret_cast<const float4*>(src + (size_t)ii * HH * WW + w4);
  }
  __syncthreads();
  int u = t & 7;
  int wl = t >> 3;
  int key = u << 2;
#pragma unroll
  for (int iter = 0; iter < 2; ++iter) {
    int w2 = wl + iter * 32;
    union { unsigned short us[8]; uintx4 v; } pk;
#pragma unroll
    for (int j = 0; j < 8; ++j) {
      int ii = u * 8 + j;
      float v = tile[ii][w2 ^ key] * ssc[ii];
      __hip_bfloat16 hb = __float2bfloat16(v);
      pk.us[j] = *reinterpret_cast<unsigned short*>(&hb);
    }
    *reinterpret_cast<uintx4*>(xs_img + (((size_t)(h + 1)) * WP + (w2 + 1)) * CI + i0 + u * 8) = pk.v;
  }
}

// ---------------- main conv: implicit GEMM ----------------
// BM=128 o x BN=256 px (4 rows x 64 cols); 256 threads = 4 waves = 2 o-groups x 2 px-groups.
// Wave-tile 64o x 128px (acc[4][8]); K-chunk = 32 i (8 chunks); per tap per wave: 4 af + 8 bq
// ds_read_b128, 32 MFMA. Rows are 64 B -> every ds_read/stage is a contiguous-1KB pattern:
// conflict-free with NO swizzle.
// LDS: X dbuf 2 x 28672 (6 stripes x 72 px x 32 i + pad block) + A ping 2 x 8192 = 73728 B
//   -> 2 blocks/CU (two independent barrier domains per CU: fills both pipes).
// Pipeline: X(c+1) staged 1 load/wave/tap over taps 2..8 of chunk c; A(gt+1) ping-pong each tap.
// No vmcnt(0) in the main loop: issue order (X then A) makes vmcnt(2)/(3) exact.
__global__ __launch_bounds__(256, 2)
void k_conv(const __hip_bfloat16* __restrict__ Xs, const __hip_bfloat16* __restrict__ Wt,
            const float* __restrict__ demod, float* __restrict__ out) {
  __shared__ __align__(16) char lds[2 * 28672 + 2 * 8192];
  char* sX0 = lds;            // 2 x 28672
  char* sA0 = lds + 57344;    // 2 x 8192

  // bijective XCD swizzle: 512 blocks -> 64 consecutive wg per XCD = 2 images per XCD L2
  int wg = (blockIdx.x & 7) * 64 + (blockIdx.x >> 3);
  int b = wg >> 5;
  int rem = wg & 31;
  int ht = rem >> 1;                    // 0..15
  int ob = rem & 1;
  int h0 = ht * 4;                      // 4 output rows
  int o0 = ob * 128;

  int tid = threadIdx.x;
  int wv = tid >> 6;                    // 0..3
  int lane = tid & 63;
  int lhi = lane >> 4;                  // 0..3
  int llo = lane & 15;                  // 0..15
  int wo2 = wv >> 1;                    // 0..1  o-group
  int wpx = wv & 1;                     // 0..1  px-group (2 rows)

  floatx4 acc[4][8];
#pragma unroll
  for (int m = 0; m < 4; ++m)
#pragma unroll
    for (int n = 0; n < 8; ++n) acc[m][n] = (floatx4){0.f, 0.f, 0.f, 0.f};

  const __hip_bfloat16* xs_img = Xs + (size_t)b * HP * WP * CI;

  // X staging slots: 28 1-KB blocks, 7 per wave (block j = wv + 4*s); pad block 27 clamps.
  int xoff[7];
#pragma unroll
  for (int s = 0; s < 7; ++s) {
    int j = wv + 4 * s;
    int pr = 16 * j + (lane >> 2);      // LDS pixel-row 0..447
    if (pr > 431) pr = 431;             // pad block: duplicate last row (never read)
    int lr = pr / 72;
    int wp = pr - lr * 72;
    if (wp > 65) wp = 65;               // pitch pad: duplicate px65 (never read)
    xoff[s] = ((h0 + lr) * WP + wp) * CI + (lane & 3) * 8;
  }
  // A staging: 8 1-KB blocks/tap, 2 per wave (block j = wv*2 + jj)
  int a_off[2];
#pragma unroll
  for (int jj = 0; jj < 2; ++jj)
    a_off[jj] = (o0 + 32 * wv + 16 * jj + (lane >> 2)) * CI + (lane & 3) * 8;

  // ---- prologue: stage X(0) fully + A(gt=0) ----
#pragma unroll
  for (int s = 0; s < 7; ++s)
    g2lds16(xs_img + xoff[s], sX0 + (wv + 4 * s) * 1024);
#pragma unroll
  for (int jj = 0; jj < 2; ++jj)
    g2lds16(Wt + a_off[jj], sA0 + (wv * 2 + jj) * 1024);
  ASM_VMCNT0();
  RAW_BAR();

  for (int c = 0; c < 8; ++c) {
    const char* xbuf = sX0 + (c & 1) * 28672;
#pragma unroll
    for (int t = 0; t < 9; ++t) {
      int gt = c * 9 + t;
      // ---- issue X(c+1) slot (taps 2..8, chunks 0..6) ----
      bool xiss = (t >= 2) && (c < 7);
      if (xiss) {
        int s = t - 2;
        g2lds16(xs_img + xoff[s] + (c + 1) * 32,
                sX0 + ((c + 1) & 1) * 28672 + (wv + 4 * s) * 1024);
      }
      // ---- issue A(gt+1) into other ping buffer ----
      if (gt < 71) {
        int nt = (t == 8) ? 0 : t + 1;
        int ncc = (t == 8) ? c + 1 : c;
        const __hip_bfloat16* wb = Wt + (size_t)nt * CO * CI + ncc * 32;
        char* ad = sA0 + ((gt + 1) & 1) * 8192;
        g2lds16(wb + a_off[0], ad + (wv * 2 + 0) * 1024);
        g2lds16(wb + a_off[1], ad + (wv * 2 + 1) * 1024);
        if (xiss) { ASM_VMCNT3(); } else { ASM_VMCNT2(); }
      } else {
        ASM_VMCNT0();
      }
      RAW_BAR();                        // A(gt) (and, at t=0, all of X(c)) landed

      const char* sA = sA0 + (gt & 1) * 8192;
      int kh = t / 3;
      int kw = t - kh * 3;
      short8 af[4];
#pragma unroll
      for (int m = 0; m < 4; ++m)
        af[m] = *reinterpret_cast<const short8*>(sA + (wo2 * 64 + m * 16 + llo) * 64 + lhi * 16);
#pragma unroll
      for (int n = 0; n < 8; ++n) {
        int stripe = wpx * 2 + (n >> 2) + kh;            // 0..5
        int px = (n & 3) * 16 + llo + kw;                // 0..65
        short8 bq = *reinterpret_cast<const short8*>(xbuf + (stripe * 72 + px) * 64 + lhi * 16);
#pragma unroll
        for (int m = 0; m < 4; ++m)
          acc[m][n] = __builtin_amdgcn_mfma_f32_16x16x32_bf16(af[m], bq, acc[m][n], 0, 0, 0);
      }
      RAW_BAR();                        // reads(gt) done -> next stage may overwrite
    }
  }

  // ---- epilogue: demod multiply, fp32 NCHW stores ----
#pragma unroll
  for (int m = 0; m < 4; ++m) {
    int obase_o = o0 + wo2 * 64 + m * 16 + lhi * 4;
    float4 dmv = *reinterpret_cast<const float4*>(demod + (size_t)b * CO + obase_o);
#pragma unroll
    for (int j = 0; j < 4; ++j) {
      int o = obase_o + j;
      float dm = (j == 0) ? dmv.x : (j == 1) ? dmv.y : (j == 2) ? dmv.z : dmv.w;
      float* orow = out + (((size_t)b * CO + o) * HH + h0) * WW;
#pragma unroll
      for (int n = 0; n < 8; ++n) {
        int row = wpx * 2 + (n >> 2);
        int col = (n & 3) * 16 + llo;
        orow[(size_t)row * WW + col] = acc[m][n][j] * dm;
      }
    }
  }
}

extern "C" void kernel_launch(void* const* d_in, const int* in_sizes, int n_in,
                              void* d_out, int out_size, void* d_ws, size_t ws_size,
                              hipStream_t stream) {
  const float* X      = (const float*)d_in[0];
  const float* cond_v = (const float*)d_in[1];
  const float* conv_w = (const float*)d_in[2];
  const float* w0     = (const float*)d_in[3];
  const float* b0     = (const float*)d_in[4];
  const float* w1     = (const float*)d_in[5];
  const float* b1     = (const float*)d_in[6];
  const float* w_out  = (const float*)d_in[7];
  const float* b_out  = (const float*)d_in[8];
  float* out = (float*)d_out;

  char* ws = (char*)d_ws;
  const size_t XS_BYTES  = (size_t)NB * HP * WP * CI * 2;
  const size_t WT_BYTES  = (size_t)9 * CO * CI * 2;
  const size_t WSQ_BYTES = (size_t)CO * CI * 4;
  __hip_bfloat16* Xs = (__hip_bfloat16*)ws;
  __hip_bfloat16* Wt = (__hip_bfloat16*)(ws + XS_BYTES);
  float* wsq   = (float*)(ws + XS_BYTES + WT_BYTES);
  float* h0b   = (float*)(ws + XS_BYTES + WT_BYTES + WSQ_BYTES);
  float* h1b   = h0b + NB * CC;
  float* scale = h1b + NB * CC;
  float* demod = scale + NB * CI;

  k_repack<<<(CO * CI) / 256, 256, 0, stream>>>(conv_w, Wt, wsq);
  k_mlp<CC, CC, true, false, 128><<<NB * (CC / 128), 128, 0, stream>>>(cond_v, w0, b0, h0b);
  k_mlp<CC, CC, true, false, 128><<<NB * (CC / 128), 128, 0, stream>>>(h0b, w1, b1, h1b);
  k_mlp<CC, CI, false, true, 128><<<NB * (CI / 128), 128, 0, stream>>>(h1b, w_out, b_out, scale);
  k_demod<<<NB, CO, 0, stream>>>(wsq, scale, demod);
  k_scalex<<<NB * 64 * 4, 256, 0, stream>>>(X, scale, Xs);
  // main conv: 512 blocks of 256 threads -> 2 blocks/CU
  k_conv<<<NB * 32, 256, 0, stream>>>(Xs, Wt, demod, out);
}

// Round 6
// 132.091 us; speedup vs baseline: 1.4280x; 1.0049x over previous
//
#include <hip/hip_runtime.h>
#include <hip/hip_bf16.h>
#include <cstdint>

#define NB 16
#define CI 256
#define CO 256
#define HH 64
#define WW 64
#define CC 512
#define HP 66
#define WP 66

typedef short short8 __attribute__((ext_vector_type(8)));
typedef float floatx4 __attribute__((ext_vector_type(4)));
typedef unsigned int uintx4 __attribute__((ext_vector_type(4)));

__device__ __forceinline__ void g2lds16(const void* g, void* l) {
  __builtin_amdgcn_global_load_lds((const __attribute__((address_space(1))) void*)g,
                                   (__attribute__((address_space(3))) void*)l, 16, 0, 0);
}

// counted-vmcnt + raw barrier primitives (__syncthreads would drain vmcnt(0))
#define ASM_VMCNT0() do { asm volatile("s_waitcnt vmcnt(0)" ::: "memory"); \
                          __builtin_amdgcn_sched_barrier(0); } while (0)
#define ASM_VMCNT2() do { asm volatile("s_waitcnt vmcnt(2)" ::: "memory"); \
                          __builtin_amdgcn_sched_barrier(0); } while (0)
#define ASM_VMCNT3() do { asm volatile("s_waitcnt vmcnt(3)" ::: "memory"); \
                          __builtin_amdgcn_sched_barrier(0); } while (0)
#define RAW_BAR() do { __builtin_amdgcn_sched_barrier(0);  \
                       __builtin_amdgcn_s_barrier();       \
                       __builtin_amdgcn_sched_barrier(0); } while (0)

// ---------------- MLP layer: out[b][j] = act(sum_k in[b][k]*w[j][k] + bias[j]) ----------------
template<int KD, int N, bool SILU, bool PLUSONE, int BJ>
__global__ void k_mlp(const float* __restrict__ in, const float* __restrict__ w,
                      const float* __restrict__ bias, float* __restrict__ out) {
  __shared__ float4 sin4[KD / 4];
  const int nb = N / BJ;
  int b = blockIdx.x / nb;
  int j = (blockIdx.x % nb) * BJ + threadIdx.x;
  const float4* in4 = reinterpret_cast<const float4*>(in + (size_t)b * KD);
  for (int k = threadIdx.x; k < KD / 4; k += BJ) sin4[k] = in4[k];
  __syncthreads();
  float acc = bias[j];
  const float4* wr = reinterpret_cast<const float4*>(w + (size_t)j * KD);
#pragma unroll 8
  for (int kk = 0; kk < KD / 4; ++kk) {
    float4 wv = wr[kk];
    float4 sv = sin4[kk];
    acc += wv.x * sv.x + wv.y * sv.y + wv.z * sv.z + wv.w * sv.w;
  }
  if (SILU) acc = acc / (1.0f + __expf(-acc));
  if (PLUSONE) acc += 1.0f;
  out[(size_t)b * N + j] = acc;
}

// ---------------- weight repack fp32 [O][I][3][3] -> bf16 Wt[t][o][i]; wsq[o][i]=sum_t w^2 ----------------
__global__ void k_repack(const float* __restrict__ cw, __hip_bfloat16* __restrict__ Wt,
                         float* __restrict__ wsq) {
  int gid = blockIdx.x * 256 + threadIdx.x;   // gid = o*CI + i
  if (gid >= CO * CI) return;
  const float* p = cw + (size_t)gid * 9;
  float s = 0.0f;
#pragma unroll
  for (int t = 0; t < 9; ++t) {
    float v = p[t];
    s += v * v;
    Wt[(size_t)t * CO * CI + gid] = __float2bfloat16(v);
  }
  wsq[gid] = s;
}

// ---------------- demod[b][o] = rsqrt(sum_i wsq[o][i]*scale[b][i]^2 + 1e-8) ----------------
__global__ void k_demod(const float* __restrict__ wsq, const float* __restrict__ scale,
                        float* __restrict__ demod) {
  __shared__ float s2[CI];
  int b = blockIdx.x;
  int o = threadIdx.x;
  float sv = scale[b * CI + o];
  s2[o] = sv * sv;
  __syncthreads();
  float acc = 0.0f;
  const float4* wr = reinterpret_cast<const float4*>(wsq + (size_t)o * CI);
  const float4* s4 = reinterpret_cast<const float4*>(s2);
#pragma unroll 8
  for (int i = 0; i < CI / 4; ++i) {
    float4 wv = wr[i];
    float4 sq = s4[i];
    acc += wv.x * sq.x + wv.y * sq.y + wv.z * sq.z + wv.w * sq.w;
  }
  demod[b * CO + o] = rsqrtf(acc + 1e-8f);
}

// ---------------- X (NCHW fp32) * scale -> Xs (padded NHWC bf16); halo zeroing fused ----------------
__global__ void k_scalex(const float* __restrict__ X, const float* __restrict__ scale,
                         __hip_bfloat16* __restrict__ Xs) {
  __shared__ float tile[64][68];
  __shared__ float ssc[64];
  int bid = blockIdx.x;                 // grid = NB * 64(h) * 4(ichunk)
  int b = bid >> 8;
  int rem = bid & 255;
  int h = rem >> 2;
  int i0 = (rem & 3) * 64;
  int t = threadIdx.x;
  if (t < 64) ssc[t] = scale[b * CI + i0 + t];

  __hip_bfloat16* xs_img = Xs + (size_t)b * HP * WP * CI;
  uintx4 z = {0u, 0u, 0u, 0u};
  if (t < 16) {
    int px = (t >> 3) * 65;
    int sl = t & 7;
    *reinterpret_cast<uintx4*>(xs_img + (((size_t)(h + 1)) * WP + px) * CI + i0 + sl * 8) = z;
  }
  if (h == 0) {
    for (int u = t; u < 66 * 8; u += 256) {
      int px = u >> 3, sl = u & 7;
      *reinterpret_cast<uintx4*>(xs_img + ((size_t)px) * CI + i0 + sl * 8) = z;
    }
  }
  if (h == 63) {
    for (int u = t; u < 66 * 8; u += 256) {
      int px = u >> 3, sl = u & 7;
      *reinterpret_cast<uintx4*>(xs_img + ((size_t)65 * WP + px) * CI + i0 + sl * 8) = z;
    }
  }

  const float* src = X + (((size_t)b * CI + i0) * HH + h) * WW;
  int ii_base = t >> 4;                 // 0..3
  int w4 = (t & 15) * 4;
#pragma unroll
  for (int r2 = 0; r2 < 4; ++r2) {
    int ii = r2 * 16 + ii_base;
    int key = ((ii >> 3) & 7) << 2;
    *reinterpret_cast<float4*>(&tile[ii][w4 ^ key]) =
        *reinterpret_cast<const float4*>(src + (size_t)ii * HH * WW + w4);
  }
  __syncthreads();
  int u = t & 7;
  int wl = t >> 3;
  int key = u << 2;
#pragma unroll
  for (int iter = 0; iter < 2; ++iter) {
    int w2 = wl + iter * 32;
    union { unsigned short us[8]; uintx4 v; } pk;
#pragma unroll
    for (int j = 0; j < 8; ++j) {
      int ii = u * 8 + j;
      float v = tile[ii][w2 ^ key] * ssc[ii];
      __hip_bfloat16 hb = __float2bfloat16(v);
      pk.us[j] = *reinterpret_cast<unsigned short*>(&hb);
    }
    *reinterpret_cast<uintx4*>(xs_img + (((size_t)(h + 1)) * WP + (w2 + 1)) * CI + i0 + u * 8) = pk.v;
  }
}

// ---------------- main conv: implicit GEMM ----------------
// BM=128 o x BN=256 px (4 rows x 64 cols); 256 threads = 4 waves = 2 o-groups x 2 px-groups.
// Wave-tile 64o x 128px (acc[4][8]); K-chunk = 32 i (8 chunks); per tap per wave: 4 af + 8 bq.
// 64-B rows: raw reads would be 8-way bank-conflicted (same-parity rows share a bank quartet).
// XOR swizzle in the k-slot dim keyed on (row>>1)&3 -> same-parity rows spread over all 4
// quartets -> 2-way (free). Swizzle applied BOTH sides: staging source i-offset and read addr.
// LDS: X dbuf 2 x 28672 + A ping 2 x 8192 = 73728 B -> 2 blocks/CU (phase-decoupled domains).
// Pipeline: X(c+1) staged 1 load/wave/tap over taps 2..8 of chunk c; A(gt+1) ping-pong each tap.
// No vmcnt(0) in the main loop. T5 setprio(1) wraps the ds_read+MFMA phase.
__global__ __launch_bounds__(256, 2)
void k_conv(const __hip_bfloat16* __restrict__ Xs, const __hip_bfloat16* __restrict__ Wt,
            const float* __restrict__ demod, float* __restrict__ out) {
  __shared__ __align__(16) char lds[2 * 28672 + 2 * 8192];
  char* sX0 = lds;            // 2 x 28672
  char* sA0 = lds + 57344;    // 2 x 8192

  // bijective XCD swizzle: 512 blocks -> 64 consecutive wg per XCD = 2 images per XCD L2
  int wg = (blockIdx.x & 7) * 64 + (blockIdx.x >> 3);
  int b = wg >> 5;
  int rem = wg & 31;
  int ht = rem >> 1;                    // 0..15
  int ob = rem & 1;
  int h0 = ht * 4;                      // 4 output rows
  int o0 = ob * 128;

  int tid = threadIdx.x;
  int wv = tid >> 6;                    // 0..3
  int lane = tid & 63;
  int lhi = lane >> 4;                  // 0..3
  int llo = lane & 15;                  // 0..15
  int wo2 = wv >> 1;                    // 0..1  o-group
  int wpx = wv & 1;                     // 0..1  px-group (2 rows)

  floatx4 acc[4][8];
#pragma unroll
  for (int m = 0; m < 4; ++m)
#pragma unroll
    for (int n = 0; n < 8; ++n) acc[m][n] = (floatx4){0.f, 0.f, 0.f, 0.f};

  const __hip_bfloat16* xs_img = Xs + (size_t)b * HP * WP * CI;

  // X staging slots: 28 1-KB blocks, 7 per wave (block j = wv + 4*s); pad block 27 clamps.
  // Source i-offset carries the read-side XOR: slot (lane&3) holds k-group (lane&3)^((pr>>1)&3).
  int xoff[7];
#pragma unroll
  for (int s = 0; s < 7; ++s) {
    int j = wv + 4 * s;
    int pr = 16 * j + (lane >> 2);      // LDS pixel-row 0..447 (unclamped = actual LDS row)
    int prc = pr > 431 ? 431 : pr;      // pad block: clamp source (never read)
    int lr = prc / 72;
    int wp = prc - lr * 72;
    if (wp > 65) wp = 65;               // pitch pad: clamp source (never read)
    int ksl = (lane & 3) ^ ((pr >> 1) & 3);
    xoff[s] = ((h0 + lr) * WP + wp) * CI + ksl * 8;
  }
  // A staging: 8 1-KB blocks/tap, 2 per wave; same both-sides XOR on the k-slot.
  int a_off[2];
#pragma unroll
  for (int jj = 0; jj < 2; ++jj) {
    int ol = 32 * wv + 16 * jj + (lane >> 2);   // o-local LDS row 0..127
    int sl = (lane & 3) ^ ((ol >> 1) & 3);
    a_off[jj] = (o0 + ol) * CI + sl * 8;
  }

  // af read rows + keys (compile-time-constant per m except llo part)
  int row_a[4], key_a[4];
#pragma unroll
  for (int m = 0; m < 4; ++m) {
    row_a[m] = wo2 * 64 + m * 16 + llo;
    key_a[m] = (row_a[m] >> 1) & 3;
  }

  // ---- prologue: stage X(0) fully + A(gt=0) ----
#pragma unroll
  for (int s = 0; s < 7; ++s)
    g2lds16(xs_img + xoff[s], sX0 + (wv + 4 * s) * 1024);
#pragma unroll
  for (int jj = 0; jj < 2; ++jj)
    g2lds16(Wt + a_off[jj], sA0 + (wv * 2 + jj) * 1024);
  ASM_VMCNT0();
  RAW_BAR();

  for (int c = 0; c < 8; ++c) {
    const char* xbuf = sX0 + (c & 1) * 28672;
#pragma unroll
    for (int t = 0; t < 9; ++t) {
      int gt = c * 9 + t;
      // ---- issue X(c+1) slot (taps 2..8, chunks 0..6) ----
      bool xiss = (t >= 2) && (c < 7);
      if (xiss) {
        int s = t - 2;
        g2lds16(xs_img + xoff[s] + (c + 1) * 32,
                sX0 + ((c + 1) & 1) * 28672 + (wv + 4 * s) * 1024);
      }
      // ---- issue A(gt+1) into other ping buffer ----
      if (gt < 71) {
        int nt = (t == 8) ? 0 : t + 1;
        int ncc = (t == 8) ? c + 1 : c;
        const __hip_bfloat16* wb = Wt + (size_t)nt * CO * CI + ncc * 32;
        char* ad = sA0 + ((gt + 1) & 1) * 8192;
        g2lds16(wb + a_off[0], ad + (wv * 2 + 0) * 1024);
        g2lds16(wb + a_off[1], ad + (wv * 2 + 1) * 1024);
        if (xiss) { ASM_VMCNT3(); } else { ASM_VMCNT2(); }
      } else {
        ASM_VMCNT0();
      }
      RAW_BAR();                        // A(gt) (and, at t=0, all of X(c)) landed

      __builtin_amdgcn_s_setprio(1);    // T5: favor this wave through the read+MFMA phase
      const char* sA = sA0 + (gt & 1) * 8192;
      int kh = t / 3;
      int kw = t - kh * 3;
      short8 af[4];
#pragma unroll
      for (int m = 0; m < 4; ++m)
        af[m] = *reinterpret_cast<const short8*>(sA + row_a[m] * 64 + ((lhi ^ key_a[m]) << 4));
#pragma unroll
      for (int n = 0; n < 8; ++n) {
        int stripe = wpx * 2 + (n >> 2) + kh;            // 0..5
        int px = (n & 3) * 16 + llo + kw;                // 0..65
        int prl = stripe * 72 + px;
        short8 bq = *reinterpret_cast<const short8*>(
            xbuf + prl * 64 + ((lhi ^ ((prl >> 1) & 3)) << 4));
#pragma unroll
        for (int m = 0; m < 4; ++m)
          acc[m][n] = __builtin_amdgcn_mfma_f32_16x16x32_bf16(af[m], bq, acc[m][n], 0, 0, 0);
      }
      __builtin_amdgcn_s_setprio(0);
      RAW_BAR();                        // reads(gt) done -> next stage may overwrite
    }
  }

  // ---- epilogue: demod multiply, fp32 NCHW stores ----
#pragma unroll
  for (int m = 0; m < 4; ++m) {
    int obase_o = o0 + wo2 * 64 + m * 16 + lhi * 4;
    float4 dmv = *reinterpret_cast<const float4*>(demod + (size_t)b * CO + obase_o);
#pragma unroll
    for (int j = 0; j < 4; ++j) {
      int o = obase_o + j;
      float dm = (j == 0) ? dmv.x : (j == 1) ? dmv.y : (j == 2) ? dmv.z : dmv.w;
      float* orow = out + (((size_t)b * CO + o) * HH + h0) * WW;
#pragma unroll
      for (int n = 0; n < 8; ++n) {
        int row = wpx * 2 + (n >> 2);
        int col = (n & 3) * 16 + llo;
        orow[(size_t)row * WW + col] = acc[m][n][j] * dm;
      }
    }
  }
}

extern "C" void kernel_launch(void* const* d_in, const int* in_sizes, int n_in,
                              void* d_out, int out_size, void* d_ws, size_t ws_size,
                              hipStream_t stream) {
  const float* X      = (const float*)d_in[0];
  const float* cond_v = (const float*)d_in[1];
  const float* conv_w = (const float*)d_in[2];
  const float* w0     = (const float*)d_in[3];
  const float* b0     = (const float*)d_in[4];
  const float* w1     = (const float*)d_in[5];
  const float* b1     = (const float*)d_in[6];
  const float* w_out  = (const float*)d_in[7];
  const float* b_out  = (const float*)d_in[8];
  float* out = (float*)d_out;

  char* ws = (char*)d_ws;
  const size_t XS_BYTES  = (size_t)NB * HP * WP * CI * 2;
  const size_t WT_BYTES  = (size_t)9 * CO * CI * 2;
  const size_t WSQ_BYTES = (size_t)CO * CI * 4;
  __hip_bfloat16* Xs = (__hip_bfloat16*)ws;
  __hip_bfloat16* Wt = (__hip_bfloat16*)(ws + XS_BYTES);
  float* wsq   = (float*)(ws + XS_BYTES + WT_BYTES);
  float* h0b   = (float*)(ws + XS_BYTES + WT_BYTES + WSQ_BYTES);
  float* h1b   = h0b + NB * CC;
  float* scale = h1b + NB * CC;
  float* demod = scale + NB * CI;

  k_repack<<<(CO * CI) / 256, 256, 0, stream>>>(conv_w, Wt, wsq);
  k_mlp<CC, CC, true, false, 128><<<NB * (CC / 128), 128, 0, stream>>>(cond_v, w0, b0, h0b);
  k_mlp<CC, CC, true, false, 128><<<NB * (CC / 128), 128, 0, stream>>>(h0b, w1, b1, h1b);
  k_mlp<CC, CI, false, true, 128><<<NB * (CI / 128), 128, 0, stream>>>(h1b, w_out, b_out, scale);
  k_demod<<<NB, CO, 0, stream>>>(wsq, scale, demod);
  k_scalex<<<NB * 64 * 4, 256, 0, stream>>>(X, scale, Xs);
  // main conv: 512 blocks of 256 threads -> 2 blocks/CU
  k_conv<<<NB * 32, 256, 0, stream>>>(Xs, Wt, demod, out);
}